// Round 5
// baseline (154.723 us; speedup 1.0000x reference)
//
#include <hip/hip_runtime.h>

#define NN  512
#define DD  128
#define NST_B 4352            // per-batch supertasks: 16 * floor(33^2/4)

typedef __attribute__((ext_vector_type(4))) float f32x4;
typedef __attribute__((ext_vector_type(8))) short s16x8;   // 8 bf16 (4 VGPRs)

#define MFMA(a, b, c) __builtin_amdgcn_mfma_f32_16x16x32_bf16((a), (b), (c), 0, 0, 0)

// LDS strides: padded -> worst 2-way (free, m136)
#define B1S 136   // 128 + 8 (ushort units)
#define H1S 68    // 64 + 4  (u32 units)

// all-16-lane sum via DPP row rotations (VALU pipe, zero DS traffic)
#define ROR_ADD(x, CTRL) \
    ((x) + __int_as_float(__builtin_amdgcn_update_dpp(0, __float_as_int(x), (CTRL), 0xF, 0xF, true)))

// fp32 -> (bf16 hi [RNA], bf16 lo [trunc of exact remainder]); hh+lh+hl ~2^-17 rel
__device__ __forceinline__ void split8(const float* __restrict__ x, s16x8& h, s16x8& l) {
    uint4 hp, lp;
    unsigned* hw = (unsigned*)&hp;
    unsigned* lw = (unsigned*)&lp;
    #pragma unroll
    for (int i = 0; i < 4; ++i) {
        float x0 = x[2 * i], x1 = x[2 * i + 1];
        unsigned t0 = __float_as_uint(x0) + 0x8000u;
        unsigned t1 = __float_as_uint(x1) + 0x8000u;
        hw[i] = __builtin_amdgcn_perm(t1, t0, 0x07060302u);
        float l0 = x0 - __uint_as_float(t0 & 0xFFFF0000u);
        float l1 = x1 - __uint_as_float(t1 & 0xFFFF0000u);
        lw[i] = __builtin_amdgcn_perm(__float_as_uint(l1), __float_as_uint(l0), 0x07060302u);
    }
    h = __builtin_bit_cast(s16x8, hp);
    l = __builtin_bit_cast(s16x8, lp);
}

// pack one fp32 into u32 = (bf16_lo << 16) | bf16_hi  (same split math)
__device__ __forceinline__ unsigned packhl(float x) {
    unsigned tt = __float_as_uint(x) + 0x8000u;
    float lo = x - __uint_as_float(tt & 0xFFFF0000u);
    return __builtin_amdgcn_perm(__float_as_uint(lo), tt, 0x07060302u);
}

// 8 packed u32 -> hi-frag and lo-frag s16x8 (2 v_perm per pair of elems)
__device__ __forceinline__ void unpack8(const unsigned* __restrict__ u, s16x8& h, s16x8& l) {
    uint4 hp, lp;
    unsigned* hw = (unsigned*)&hp;
    unsigned* lw = (unsigned*)&lp;
    #pragma unroll
    for (int i = 0; i < 4; ++i) {
        hw[i] = __builtin_amdgcn_perm(u[2 * i + 1], u[2 * i], 0x05040100u);
        lw[i] = __builtin_amdgcn_perm(u[2 * i + 1], u[2 * i], 0x07060302u);
    }
    h = __builtin_bit_cast(s16x8, hp);
    l = __builtin_bit_cast(s16x8, lp);
}

// -------- layer-1 one K-chunk (compile-time KT), both j-tiles, shared B ------
#define L1KT(KT) do {                                                          \
    float xA8[8], xB8[8], d8[8];                                               \
    *(float4*)&xA8[0] = *(const float4*)(vrA + (KT) * 32 + q8);                \
    *(float4*)&xA8[4] = *(const float4*)(vrA + (KT) * 32 + q8 + 4);            \
    *(float4*)&xB8[0] = *(const float4*)(vrB + (KT) * 32 + q8);                \
    *(float4*)&xB8[4] = *(const float4*)(vrB + (KT) * 32 + q8 + 4);            \
    s16x8 ahA, alA, ahB, alB;                                                  \
    _Pragma("unroll")                                                          \
    for (int ii = 0; ii < 8; ++ii) d8[ii] = fabsf(yv[KT][ii] - xA8[ii]);       \
    split8(d8, ahA, alA);                                                      \
    _Pragma("unroll")                                                          \
    for (int ii = 0; ii < 8; ++ii) d8[ii] = fabsf(yv[KT][ii] - xB8[ii]);       \
    split8(d8, ahB, alB);                                                      \
    _Pragma("unroll")                                                          \
    for (int ot = 0; ot < 4; ++ot) {                                           \
        const int n = ot * 16 + m16;                                           \
        s16x8 bh = *(const s16x8*)(B1h_s + n * B1S + (KT) * 32 + q8);          \
        s16x8 bl = *(const s16x8*)(B1l_s + n * B1S + (KT) * 32 + q8);          \
        cA[ot] = MFMA(ahA, bh, cA[ot]);                                        \
        cB[ot] = MFMA(ahB, bh, cB[ot]);                                        \
        cA[ot] = MFMA(alA, bh, cA[ot]);                                        \
        cB[ot] = MFMA(alB, bh, cB[ot]);                                        \
        cA[ot] = MFMA(ahA, bl, cA[ot]);                                        \
        cB[ot] = MFMA(ahB, bl, cB[ot]);                                        \
    }                                                                          \
} while (0)

// -------- per-tile tail: h1 -> layer2 (reg B) -> layer3 -> store -------------
#define TAIL(CACC, JT) do {                                                    \
    _Pragma("unroll")                                                          \
    for (int ot = 0; ot < 4; ++ot)                                             \
        _Pragma("unroll")                                                      \
        for (int rr = 0; rr < 4; ++rr) {                                       \
            float hv = CACC[ot][rr] + b1v[ot];                                 \
            hv = fmaxf(hv, 0.1f * hv);                                         \
            h1p_s[(w * 16 + q * 4 + rr) * H1S + ot * 16 + m16] = packhl(hv);   \
        }                                                                      \
    f32x4 dacc0 = (f32x4){0.f, 0.f, 0.f, 0.f};                                 \
    f32x4 dacc1 = (f32x4){0.f, 0.f, 0.f, 0.f};                                 \
    _Pragma("unroll")                                                          \
    for (int kt2 = 0; kt2 < 2; ++kt2) {                                        \
        const unsigned* hp = h1p_s + (w * 16 + m16) * H1S + kt2 * 32 + q8;     \
        unsigned u[8];                                                         \
        *(uint4*)&u[0] = *(const uint4*)hp;                                    \
        *(uint4*)&u[4] = *(const uint4*)(hp + 4);                              \
        s16x8 ah, al;                                                          \
        unpack8(u, ah, al);                                                    \
        dacc0 = MFMA(ah, B2h_r[kt2][0], dacc0);                                \
        dacc1 = MFMA(ah, B2h_r[kt2][1], dacc1);                                \
        dacc0 = MFMA(al, B2h_r[kt2][0], dacc0);                                \
        dacc1 = MFMA(al, B2h_r[kt2][1], dacc1);                                \
        dacc0 = MFMA(ah, B2l_r[kt2][0], dacc0);                                \
        dacc1 = MFMA(ah, B2l_r[kt2][1], dacc1);                                \
    }                                                                          \
    float sval0, sval1, sval2, sval3;                                          \
    {                                                                          \
        float h0, h1v, sc;                                                     \
        h0 = dacc0[0] + b2v0; h0 = fmaxf(h0, 0.1f * h0);                       \
        h1v = dacc1[0] + b2v1; h1v = fmaxf(h1v, 0.1f * h1v);                   \
        sc = fmaf(w3v0, h0, w3v1 * h1v);                                       \
        sc = ROR_ADD(sc, 0x121); sc = ROR_ADD(sc, 0x122);                      \
        sc = ROR_ADD(sc, 0x124); sc = ROR_ADD(sc, 0x128);                      \
        sval0 = sc + b3v;                                                      \
        h0 = dacc0[1] + b2v0; h0 = fmaxf(h0, 0.1f * h0);                       \
        h1v = dacc1[1] + b2v1; h1v = fmaxf(h1v, 0.1f * h1v);                   \
        sc = fmaf(w3v0, h0, w3v1 * h1v);                                       \
        sc = ROR_ADD(sc, 0x121); sc = ROR_ADD(sc, 0x122);                      \
        sc = ROR_ADD(sc, 0x124); sc = ROR_ADD(sc, 0x128);                      \
        sval1 = sc + b3v;                                                      \
        h0 = dacc0[2] + b2v0; h0 = fmaxf(h0, 0.1f * h0);                       \
        h1v = dacc1[2] + b2v1; h1v = fmaxf(h1v, 0.1f * h1v);                   \
        sc = fmaf(w3v0, h0, w3v1 * h1v);                                       \
        sc = ROR_ADD(sc, 0x121); sc = ROR_ADD(sc, 0x122);                      \
        sc = ROR_ADD(sc, 0x124); sc = ROR_ADD(sc, 0x128);                      \
        sval2 = sc + b3v;                                                      \
        h0 = dacc0[3] + b2v0; h0 = fmaxf(h0, 0.1f * h0);                       \
        h1v = dacc1[3] + b2v1; h1v = fmaxf(h1v, 0.1f * h1v);                   \
        sc = fmaf(w3v0, h0, w3v1 * h1v);                                       \
        sc = ROR_ADD(sc, 0x121); sc = ROR_ADD(sc, 0x122);                      \
        sc = ROR_ADD(sc, 0x124); sc = ROR_ADD(sc, 0x128);                      \
        sval3 = sc + b3v;                                                      \
    }                                                                          \
    float vv = sval0;                                                          \
    vv = ((lane & 3) == 1) ? sval1 : vv;                                       \
    vv = ((lane & 3) == 2) ? sval2 : vv;                                       \
    vv = ((lane & 3) == 3) ? sval3 : vv;                                       \
    const float pv = __shfl(vv, (((lane & 15) >> 2) << 4) | (lane & 3), 64);   \
    if (lane < 32) {                                                           \
        const size_t addr = (lane < 16)                                        \
            ? (vb + (unsigned)i) * NN + (unsigned)((JT) + (lane & 15))         \
            : (vb + (unsigned)((JT) + (lane & 15))) * NN + (unsigned)i;        \
        out[addr] = pv;                                                        \
    }                                                                          \
} while (0)

// ---------------------------------------------------------------------------
// Symmetric logits, 2-j-tile supertasks; waves_per_eu pinned to 2 so the
// allocator gets the full 256-VGPR budget (LDS caps us at 2 blocks/CU anyway).
// 512 persistent blocks x 4 waves; LDS 52224 B; h1 rows wave-private.
// ---------------------------------------------------------------------------
__global__ __launch_bounds__(256)
__attribute__((amdgpu_waves_per_eu(2, 2)))
void adj_sym5(const float* __restrict__ v,
              const float* __restrict__ W1,
              const float* __restrict__ b1,
              const float* __restrict__ W2,
              const float* __restrict__ b2,
              const float* __restrict__ W3,
              const float* __restrict__ b3,
              float* __restrict__ out)
{
    __shared__ __attribute__((aligned(16))) unsigned short B1h_s[64 * B1S];
    __shared__ __attribute__((aligned(16))) unsigned short B1l_s[64 * B1S];
    __shared__ __attribute__((aligned(16))) unsigned h1p_s[64 * H1S];

    const int t    = threadIdx.x;
    const int w    = t >> 6;
    const int lane = t & 63;
    const int m16  = t & 15;
    const int q    = (t & 63) >> 4;
    const int q8   = q * 8;

    // ---- prologue: W1 split into LDS, vectorized (8 x float4 per thread) ----
    #pragma unroll
    for (int e = 0; e < 8; ++e) {
        int idx4 = e * 256 + t;
        int o = idx4 >> 5;
        int d = (idx4 & 31) * 4;
        float4 x = *(const float4*)(W1 + idx4 * 4);
        float xs[4] = {x.x, x.y, x.z, x.w};
        unsigned tb[4], lb[4];
        #pragma unroll
        for (int k2 = 0; k2 < 4; ++k2) {
            tb[k2] = __float_as_uint(xs[k2]) + 0x8000u;
            float lo = xs[k2] - __uint_as_float(tb[k2] & 0xFFFF0000u);
            lb[k2] = __float_as_uint(lo);
        }
        uint2 hw, lw;
        hw.x = __builtin_amdgcn_perm(tb[1], tb[0], 0x07060302u);
        hw.y = __builtin_amdgcn_perm(tb[3], tb[2], 0x07060302u);
        lw.x = __builtin_amdgcn_perm(lb[1], lb[0], 0x07060302u);
        lw.y = __builtin_amdgcn_perm(lb[3], lb[2], 0x07060302u);
        *(uint2*)(B1h_s + o * B1S + d) = hw;
        *(uint2*)(B1l_s + o * B1S + d) = lw;
    }

    // ---- W2 fragments -> registers (once per wave; layer-2 B = 0 DS) ----
    s16x8 B2h_r[2][2], B2l_r[2][2];
    #pragma unroll
    for (int kt2 = 0; kt2 < 2; ++kt2)
        #pragma unroll
        for (int ot2 = 0; ot2 < 2; ++ot2) {
            const float* wp = W2 + (ot2 * 16 + m16) * 64 + kt2 * 32 + q8;
            float a8[8];
            *(float4*)&a8[0] = *(const float4*)wp;
            *(float4*)&a8[4] = *(const float4*)(wp + 4);
            split8(a8, B2h_r[kt2][ot2], B2l_r[kt2][ot2]);
        }

    float b1v[4];
    #pragma unroll
    for (int ot = 0; ot < 4; ++ot) b1v[ot] = b1[ot * 16 + m16];
    const float b2v0 = b2[m16];
    const float b2v1 = b2[16 + m16];
    const float w3v0 = W3[m16];
    const float w3v1 = W3[16 + m16];
    const float b3v  = b3[0];

    __syncthreads();   // B1 ready; waves drift freely afterwards

    // ---- static per-wave chunk of the 17408 supertasks (8.5/wave) ----
    const int g    = blockIdx.x * 4 + w;
    int       tk   = (17 * g) >> 1;
    const int tend = (17 * (g + 1)) >> 1;

    // decode tk -> (bb, G, s, gj2); P(G) = 16*floor((G+1)^2/4)
    unsigned bb = (unsigned)tk / (unsigned)NST_B;
    int r = tk - (int)(bb * NST_B);
    int G = (int)__fsqrt_rn((float)r * 0.25f + 1.0f) - 1;
    if (G < 0) G = 0;
    if (G > 31) G = 31;
    while (G < 31 && 16 * (((G + 2) * (G + 2)) >> 2) <= r) ++G;
    while (G > 0 && 16 * (((G + 1) * (G + 1)) >> 2) > r) --G;
    int rem = r - 16 * (((G + 1) * (G + 1)) >> 2);
    int nG  = (G >> 1) + 1;
    int s   = rem / nG;
    int gj2 = rem - s * nG;
    bool newi = true;

    float yv[4][8];

    #pragma unroll 1
    for (; tk < tend; ++tk) {
        const size_t vb = (size_t)bb << 9;
        const int    i  = (G << 4) + s;
        const int    j0 = gj2 << 5;
        const bool   v2 = (2 * gj2 + 1) <= G;   // wave-uniform

        if (newi) {
            const float* __restrict__ vip = v + (vb + (unsigned)i) * DD;
            #pragma unroll
            for (int kt = 0; kt < 4; ++kt) {
                *(float4*)&yv[kt][0] = *(const float4*)(vip + kt * 32 + q8);
                *(float4*)&yv[kt][4] = *(const float4*)(vip + kt * 32 + q8 + 4);
            }
        }

        const float* __restrict__ vrA = v + (vb + (unsigned)(j0 + m16)) * DD;
        const float* __restrict__ vrB = vrA + 16 * DD;

        // ======== layer 1: 32 pairs x 64 cols, K=128; B-frags read ONCE ======
        f32x4 cA[4], cB[4];
        #pragma unroll
        for (int ot = 0; ot < 4; ++ot) {
            cA[ot] = (f32x4){0.f, 0.f, 0.f, 0.f};
            cB[ot] = (f32x4){0.f, 0.f, 0.f, 0.f};
        }
        L1KT(0);
        L1KT(1);
        L1KT(2);
        L1KT(3);

        // ======== per-tile tails (fully inlined) ========
        TAIL(cA, j0);
        if (v2) {
            TAIL(cB, j0 + 16);
        }

        // ---- incremental advance ----
        ++gj2; newi = false;
        if (gj2 == nG) {
            gj2 = 0; newi = true;
            if (++s == 16) {
                s = 0;
                if (++G == 32) { G = 0; ++bb; }
                nG = (G >> 1) + 1;
            }
        }
    }
}

// ---------------------------------------------------------------------------
// In-place row softmax over the 512 logits of each (b,i) row.
// ---------------------------------------------------------------------------
__global__ __launch_bounds__(256)
void row_softmax(float* __restrict__ out)
{
    __shared__ float red[8];
    const int t    = threadIdx.x;
    const int w    = t >> 6;
    const int lane = t & 63;

    float* orow = out + (size_t)blockIdx.x * NN;
    float a0 = orow[t];
    float a1 = orow[t + 256];

    float m = fmaxf(a0, a1);
    #pragma unroll
    for (int sh = 32; sh > 0; sh >>= 1)
        m = fmaxf(m, __shfl_xor(m, sh, 64));
    if (lane == 0) red[w] = m;
    __syncthreads();
    const float M = fmaxf(fmaxf(red[0], red[1]), fmaxf(red[2], red[3]));

    float e0 = __expf(a0 - M);
    float e1 = __expf(a1 - M);
    float s01 = e0 + e1;
    #pragma unroll
    for (int sh = 32; sh > 0; sh >>= 1)
        s01 += __shfl_xor(s01, sh, 64);
    if (lane == 0) red[4 + w] = s01;
    __syncthreads();
    const float S = (red[4] + red[5]) + (red[6] + red[7]);
    const float inv = 1.0f / S;

    orow[t]       = e0 * inv;
    orow[t + 256] = e1 * inv;
}

extern "C" void kernel_launch(void* const* d_in, const int* in_sizes, int n_in,
                              void* d_out, int out_size, void* d_ws, size_t ws_size,
                              hipStream_t stream) {
    const float* v  = (const float*)d_in[0];
    const float* W1 = (const float*)d_in[1];
    const float* b1 = (const float*)d_in[2];
    const float* W2 = (const float*)d_in[3];
    const float* b2 = (const float*)d_in[4];
    const float* W3 = (const float*)d_in[5];
    const float* b3 = (const float*)d_in[6];
    float* out = (float*)d_out;

    adj_sym5<<<dim3(512), dim3(256), 0, stream>>>(v, W1, b1, W2, b2, W3, b3, out);
    row_softmax<<<dim3(4 * NN), dim3(256), 0, stream>>>(out);
}

// Round 6
// 145.154 us; speedup vs baseline: 1.0659x; 1.0659x over previous
//
#include <hip/hip_runtime.h>

#define NN  512
#define DD  128
#define NST_B 4352            // per-batch supertasks: 16 * floor(33^2/4)

typedef __attribute__((ext_vector_type(4))) float f32x4;
typedef __attribute__((ext_vector_type(8))) short s16x8;   // 8 bf16 (4 VGPRs)

#define MFMA(a, b, c) __builtin_amdgcn_mfma_f32_16x16x32_bf16((a), (b), (c), 0, 0, 0)

// LDS strides: padded -> worst 2-way (free, m136)
#define B1S 136   // 128 + 8 (ushort units)
#define B2S 72    // 64 + 8  (ushort units)
#define H1S 68    // 64 + 4  (u32 units)

// all-16-lane sum via DPP row rotations (VALU pipe, zero DS traffic)
#define ROR_ADD(x, CTRL) \
    ((x) + __int_as_float(__builtin_amdgcn_update_dpp(0, __float_as_int(x), (CTRL), 0xF, 0xF, true)))

// fp32 -> (bf16 hi [RNA], bf16 lo [trunc of exact remainder]); hh+lh+hl ~2^-17 rel
__device__ __forceinline__ void split8(const float* __restrict__ x, s16x8& h, s16x8& l) {
    uint4 hp, lp;
    unsigned* hw = (unsigned*)&hp;
    unsigned* lw = (unsigned*)&lp;
    #pragma unroll
    for (int i = 0; i < 4; ++i) {
        float x0 = x[2 * i], x1 = x[2 * i + 1];
        unsigned t0 = __float_as_uint(x0) + 0x8000u;
        unsigned t1 = __float_as_uint(x1) + 0x8000u;
        hw[i] = __builtin_amdgcn_perm(t1, t0, 0x07060302u);
        float l0 = x0 - __uint_as_float(t0 & 0xFFFF0000u);
        float l1 = x1 - __uint_as_float(t1 & 0xFFFF0000u);
        lw[i] = __builtin_amdgcn_perm(__float_as_uint(l1), __float_as_uint(l0), 0x07060302u);
    }
    h = __builtin_bit_cast(s16x8, hp);
    l = __builtin_bit_cast(s16x8, lp);
}

__device__ __forceinline__ void split1(float x, unsigned short& hs, unsigned short& ls) {
    unsigned tt = __float_as_uint(x) + 0x8000u;
    hs = (unsigned short)(tt >> 16);
    float lo = x - __uint_as_float(tt & 0xFFFF0000u);
    ls = (unsigned short)(__float_as_uint(lo) >> 16);
}

// pack one fp32 into u32 = (bf16_lo << 16) | bf16_hi  (same split math)
__device__ __forceinline__ unsigned packhl(float x) {
    unsigned tt = __float_as_uint(x) + 0x8000u;
    float lo = x - __uint_as_float(tt & 0xFFFF0000u);
    return __builtin_amdgcn_perm(__float_as_uint(lo), tt, 0x07060302u);
}

// 8 packed u32 -> hi-frag and lo-frag s16x8 (2 v_perm per pair of elems)
__device__ __forceinline__ void unpack8(const unsigned* __restrict__ u, s16x8& h, s16x8& l) {
    uint4 hp, lp;
    unsigned* hw = (unsigned*)&hp;
    unsigned* lw = (unsigned*)&lp;
    #pragma unroll
    for (int i = 0; i < 4; ++i) {
        hw[i] = __builtin_amdgcn_perm(u[2 * i + 1], u[2 * i], 0x05040100u);
        lw[i] = __builtin_amdgcn_perm(u[2 * i + 1], u[2 * i], 0x07060302u);
    }
    h = __builtin_bit_cast(s16x8, hp);
    l = __builtin_bit_cast(s16x8, lp);
}

// -------- layer-1 one K-chunk (compile-time KT), both j-tiles, shared B ------
// Transients scoped so xA8 is dead before xB8 loads (keeps peak < 128 VGPR).
#define L1KT(KT) do {                                                          \
    s16x8 ahA, alA, ahB, alB;                                                  \
    {                                                                          \
        float x8[8], d8[8];                                                    \
        *(float4*)&x8[0] = *(const float4*)(vrA + (KT) * 32 + q8);             \
        *(float4*)&x8[4] = *(const float4*)(vrA + (KT) * 32 + q8 + 4);         \
        _Pragma("unroll")                                                      \
        for (int ii = 0; ii < 8; ++ii) d8[ii] = fabsf(yv[KT][ii] - x8[ii]);    \
        split8(d8, ahA, alA);                                                  \
    }                                                                          \
    {                                                                          \
        float x8[8], d8[8];                                                    \
        *(float4*)&x8[0] = *(const float4*)(vrB + (KT) * 32 + q8);             \
        *(float4*)&x8[4] = *(const float4*)(vrB + (KT) * 32 + q8 + 4);         \
        _Pragma("unroll")                                                      \
        for (int ii = 0; ii < 8; ++ii) d8[ii] = fabsf(yv[KT][ii] - x8[ii]);    \
        split8(d8, ahB, alB);                                                  \
    }                                                                          \
    _Pragma("unroll")                                                          \
    for (int ot = 0; ot < 4; ++ot) {                                           \
        const int n = ot * 16 + m16;                                           \
        s16x8 bh = *(const s16x8*)(B1h_s + n * B1S + (KT) * 32 + q8);          \
        s16x8 bl = *(const s16x8*)(B1l_s + n * B1S + (KT) * 32 + q8);          \
        cA[ot] = MFMA(ahA, bh, cA[ot]);                                        \
        cB[ot] = MFMA(ahB, bh, cB[ot]);                                        \
        cA[ot] = MFMA(alA, bh, cA[ot]);                                        \
        cB[ot] = MFMA(alB, bh, cB[ot]);                                        \
        cA[ot] = MFMA(ahA, bl, cA[ot]);                                        \
        cB[ot] = MFMA(ahB, bl, cB[ot]);                                        \
    }                                                                          \
} while (0)

// -------- per-tile tail: h1 -> layer2 (LDS B2) -> layer3 -> store ------------
#define TAIL(CACC, JT) do {                                                    \
    _Pragma("unroll")                                                          \
    for (int ot = 0; ot < 4; ++ot)                                             \
        _Pragma("unroll")                                                      \
        for (int rr = 0; rr < 4; ++rr) {                                       \
            float hv = CACC[ot][rr] + b1v[ot];                                 \
            hv = fmaxf(hv, 0.1f * hv);                                         \
            h1p_s[(w * 16 + q * 4 + rr) * H1S + ot * 16 + m16] = packhl(hv);   \
        }                                                                      \
    f32x4 dacc0 = (f32x4){0.f, 0.f, 0.f, 0.f};                                 \
    f32x4 dacc1 = (f32x4){0.f, 0.f, 0.f, 0.f};                                 \
    _Pragma("unroll")                                                          \
    for (int kt2 = 0; kt2 < 2; ++kt2) {                                        \
        const unsigned* hp = h1p_s + (w * 16 + m16) * H1S + kt2 * 32 + q8;     \
        unsigned u[8];                                                         \
        *(uint4*)&u[0] = *(const uint4*)hp;                                    \
        *(uint4*)&u[4] = *(const uint4*)(hp + 4);                              \
        s16x8 ah, al;                                                          \
        unpack8(u, ah, al);                                                    \
        {                                                                      \
            s16x8 bh = *(const s16x8*)(B2h_s + m16 * B2S + kt2 * 32 + q8);     \
            s16x8 bl = *(const s16x8*)(B2l_s + m16 * B2S + kt2 * 32 + q8);     \
            dacc0 = MFMA(ah, bh, dacc0);                                       \
            dacc0 = MFMA(al, bh, dacc0);                                       \
            dacc0 = MFMA(ah, bl, dacc0);                                       \
        }                                                                      \
        {                                                                      \
            s16x8 bh = *(const s16x8*)(B2h_s + (16 + m16) * B2S + kt2 * 32 + q8); \
            s16x8 bl = *(const s16x8*)(B2l_s + (16 + m16) * B2S + kt2 * 32 + q8); \
            dacc1 = MFMA(ah, bh, dacc1);                                       \
            dacc1 = MFMA(al, bh, dacc1);                                       \
            dacc1 = MFMA(ah, bl, dacc1);                                       \
        }                                                                      \
    }                                                                          \
    float sval0, sval1, sval2, sval3;                                          \
    {                                                                          \
        float h0, h1v, sc;                                                     \
        h0 = dacc0[0] + b2v0; h0 = fmaxf(h0, 0.1f * h0);                       \
        h1v = dacc1[0] + b2v1; h1v = fmaxf(h1v, 0.1f * h1v);                   \
        sc = fmaf(w3v0, h0, w3v1 * h1v);                                       \
        sc = ROR_ADD(sc, 0x121); sc = ROR_ADD(sc, 0x122);                      \
        sc = ROR_ADD(sc, 0x124); sc = ROR_ADD(sc, 0x128);                      \
        sval0 = sc + b3v;                                                      \
        h0 = dacc0[1] + b2v0; h0 = fmaxf(h0, 0.1f * h0);                       \
        h1v = dacc1[1] + b2v1; h1v = fmaxf(h1v, 0.1f * h1v);                   \
        sc = fmaf(w3v0, h0, w3v1 * h1v);                                       \
        sc = ROR_ADD(sc, 0x121); sc = ROR_ADD(sc, 0x122);                      \
        sc = ROR_ADD(sc, 0x124); sc = ROR_ADD(sc, 0x128);                      \
        sval1 = sc + b3v;                                                      \
        h0 = dacc0[2] + b2v0; h0 = fmaxf(h0, 0.1f * h0);                       \
        h1v = dacc1[2] + b2v1; h1v = fmaxf(h1v, 0.1f * h1v);                   \
        sc = fmaf(w3v0, h0, w3v1 * h1v);                                       \
        sc = ROR_ADD(sc, 0x121); sc = ROR_ADD(sc, 0x122);                      \
        sc = ROR_ADD(sc, 0x124); sc = ROR_ADD(sc, 0x128);                      \
        sval2 = sc + b3v;                                                      \
        h0 = dacc0[3] + b2v0; h0 = fmaxf(h0, 0.1f * h0);                       \
        h1v = dacc1[3] + b2v1; h1v = fmaxf(h1v, 0.1f * h1v);                   \
        sc = fmaf(w3v0, h0, w3v1 * h1v);                                       \
        sc = ROR_ADD(sc, 0x121); sc = ROR_ADD(sc, 0x122);                      \
        sc = ROR_ADD(sc, 0x124); sc = ROR_ADD(sc, 0x128);                      \
        sval3 = sc + b3v;                                                      \
    }                                                                          \
    float vv = sval0;                                                          \
    vv = ((lane & 3) == 1) ? sval1 : vv;                                       \
    vv = ((lane & 3) == 2) ? sval2 : vv;                                       \
    vv = ((lane & 3) == 3) ? sval3 : vv;                                       \
    const float pv = __shfl(vv, (((lane & 15) >> 2) << 4) | (lane & 3), 64);   \
    if (lane < 32) {                                                           \
        const size_t addr = (lane < 16)                                        \
            ? (vb + (unsigned)i) * NN + (unsigned)((JT) + (lane & 15))         \
            : (vb + (unsigned)((JT) + (lane & 15))) * NN + (unsigned)i;        \
        out[addr] = pv;                                                        \
    }                                                                          \
} while (0)

// ---------------------------------------------------------------------------
// Symmetric logits, 2-j-tile supertasks; W2 back in LDS so the live set fits
// the ~128 arch-VGPR budget (round-2/4 regression = spill traffic from
// W2-in-regs). 512 persistent blocks x 4 waves; LDS 61440 B -> 2 blocks/CU.
// ---------------------------------------------------------------------------
__global__ __launch_bounds__(256, 2)
void adj_sym6(const float* __restrict__ v,
              const float* __restrict__ W1,
              const float* __restrict__ b1,
              const float* __restrict__ W2,
              const float* __restrict__ b2,
              const float* __restrict__ W3,
              const float* __restrict__ b3,
              float* __restrict__ out)
{
    __shared__ __attribute__((aligned(16))) unsigned short B1h_s[64 * B1S];
    __shared__ __attribute__((aligned(16))) unsigned short B1l_s[64 * B1S];
    __shared__ __attribute__((aligned(16))) unsigned short B2h_s[32 * B2S];
    __shared__ __attribute__((aligned(16))) unsigned short B2l_s[32 * B2S];
    __shared__ __attribute__((aligned(16))) unsigned h1p_s[64 * H1S];

    const int t    = threadIdx.x;
    const int w    = t >> 6;
    const int lane = t & 63;
    const int m16  = t & 15;
    const int q    = (t & 63) >> 4;
    const int q8   = q * 8;

    // ---- prologue: W1 split into LDS, vectorized (8 x float4 per thread) ----
    #pragma unroll
    for (int e = 0; e < 8; ++e) {
        int idx4 = e * 256 + t;
        int o = idx4 >> 5;
        int d = (idx4 & 31) * 4;
        float4 x = *(const float4*)(W1 + idx4 * 4);
        float xs[4] = {x.x, x.y, x.z, x.w};
        unsigned tb[4], lb[4];
        #pragma unroll
        for (int k2 = 0; k2 < 4; ++k2) {
            tb[k2] = __float_as_uint(xs[k2]) + 0x8000u;
            float lo = xs[k2] - __uint_as_float(tb[k2] & 0xFFFF0000u);
            lb[k2] = __float_as_uint(lo);
        }
        uint2 hw, lw;
        hw.x = __builtin_amdgcn_perm(tb[1], tb[0], 0x07060302u);
        hw.y = __builtin_amdgcn_perm(tb[3], tb[2], 0x07060302u);
        lw.x = __builtin_amdgcn_perm(lb[1], lb[0], 0x07060302u);
        lw.y = __builtin_amdgcn_perm(lb[3], lb[2], 0x07060302u);
        *(uint2*)(B1h_s + o * B1S + d) = hw;
        *(uint2*)(B1l_s + o * B1S + d) = lw;
    }

    // ---- W2 split into LDS (32x64 = 2048 elems) ----
    #pragma unroll
    for (int e = 0; e < 8; ++e) {
        int idx = e * 256 + t;
        unsigned short hs, ls;
        split1(W2[idx], hs, ls);
        int c2 = idx >> 6, k = idx & 63;
        B2h_s[c2 * B2S + k] = hs;
        B2l_s[c2 * B2S + k] = ls;
    }

    float b1v[4];
    #pragma unroll
    for (int ot = 0; ot < 4; ++ot) b1v[ot] = b1[ot * 16 + m16];
    const float b2v0 = b2[m16];
    const float b2v1 = b2[16 + m16];
    const float w3v0 = W3[m16];
    const float w3v1 = W3[16 + m16];
    const float b3v  = b3[0];

    __syncthreads();   // B1/B2 ready; waves drift freely afterwards

    // ---- static per-wave chunk of the 17408 supertasks (8.5/wave) ----
    const int g    = blockIdx.x * 4 + w;
    int       tk   = (17 * g) >> 1;
    const int tend = (17 * (g + 1)) >> 1;

    // decode tk -> (bb, G, s, gj2); P(G) = 16*floor((G+1)^2/4)
    unsigned bb = (unsigned)tk / (unsigned)NST_B;
    int r = tk - (int)(bb * NST_B);
    int G = (int)__fsqrt_rn((float)r * 0.25f + 1.0f) - 1;
    if (G < 0) G = 0;
    if (G > 31) G = 31;
    while (G < 31 && 16 * (((G + 2) * (G + 2)) >> 2) <= r) ++G;
    while (G > 0 && 16 * (((G + 1) * (G + 1)) >> 2) > r) --G;
    int rem = r - 16 * (((G + 1) * (G + 1)) >> 2);
    int nG  = (G >> 1) + 1;
    int s   = rem / nG;
    int gj2 = rem - s * nG;
    bool newi = true;

    float yv[4][8];

    #pragma unroll 1
    for (; tk < tend; ++tk) {
        const size_t vb = (size_t)bb << 9;
        const int    i  = (G << 4) + s;
        const int    j0 = gj2 << 5;
        const bool   v2 = (2 * gj2 + 1) <= G;   // wave-uniform

        if (newi) {
            const float* __restrict__ vip = v + (vb + (unsigned)i) * DD;
            #pragma unroll
            for (int kt = 0; kt < 4; ++kt) {
                *(float4*)&yv[kt][0] = *(const float4*)(vip + kt * 32 + q8);
                *(float4*)&yv[kt][4] = *(const float4*)(vip + kt * 32 + q8 + 4);
            }
        }

        const float* __restrict__ vrA = v + (vb + (unsigned)(j0 + m16)) * DD;
        const float* __restrict__ vrB = vrA + 16 * DD;

        // ======== layer 1: 32 pairs x 64 cols, K=128; B-frags read ONCE ======
        f32x4 cA[4], cB[4];
        #pragma unroll
        for (int ot = 0; ot < 4; ++ot) {
            cA[ot] = (f32x4){0.f, 0.f, 0.f, 0.f};
            cB[ot] = (f32x4){0.f, 0.f, 0.f, 0.f};
        }
        L1KT(0);
        L1KT(1);
        L1KT(2);
        L1KT(3);

        // ======== per-tile tails (fully inlined) ========
        TAIL(cA, j0);
        if (v2) {
            TAIL(cB, j0 + 16);
        }

        // ---- incremental advance ----
        ++gj2; newi = false;
        if (gj2 == nG) {
            gj2 = 0; newi = true;
            if (++s == 16) {
                s = 0;
                if (++G == 32) { G = 0; ++bb; }
                nG = (G >> 1) + 1;
            }
        }
    }
}

// ---------------------------------------------------------------------------
// In-place row softmax over the 512 logits of each (b,i) row.
// ---------------------------------------------------------------------------
__global__ __launch_bounds__(256)
void row_softmax(float* __restrict__ out)
{
    __shared__ float red[8];
    const int t    = threadIdx.x;
    const int w    = t >> 6;
    const int lane = t & 63;

    float* orow = out + (size_t)blockIdx.x * NN;
    float a0 = orow[t];
    float a1 = orow[t + 256];

    float m = fmaxf(a0, a1);
    #pragma unroll
    for (int sh = 32; sh > 0; sh >>= 1)
        m = fmaxf(m, __shfl_xor(m, sh, 64));
    if (lane == 0) red[w] = m;
    __syncthreads();
    const float M = fmaxf(fmaxf(red[0], red[1]), fmaxf(red[2], red[3]));

    float e0 = __expf(a0 - M);
    float e1 = __expf(a1 - M);
    float s01 = e0 + e1;
    #pragma unroll
    for (int sh = 32; sh > 0; sh >>= 1)
        s01 += __shfl_xor(s01, sh, 64);
    if (lane == 0) red[4 + w] = s01;
    __syncthreads();
    const float S = (red[4] + red[5]) + (red[6] + red[7]);
    const float inv = 1.0f / S;

    orow[t]       = e0 * inv;
    orow[t + 256] = e1 * inv;
}

extern "C" void kernel_launch(void* const* d_in, const int* in_sizes, int n_in,
                              void* d_out, int out_size, void* d_ws, size_t ws_size,
                              hipStream_t stream) {
    const float* v  = (const float*)d_in[0];
    const float* W1 = (const float*)d_in[1];
    const float* b1 = (const float*)d_in[2];
    const float* W2 = (const float*)d_in[3];
    const float* b2 = (const float*)d_in[4];
    const float* W3 = (const float*)d_in[5];
    const float* b3 = (const float*)d_in[6];
    float* out = (float*)d_out;

    adj_sym6<<<dim3(512), dim3(256), 0, stream>>>(v, W1, b1, W2, b2, W3, b3, out);
    row_softmax<<<dim3(4 * NN), dim3(256), 0, stream>>>(out);
}